// Round 2
// baseline (81.534 us; speedup 1.0000x reference)
//
#include <hip/hip_runtime.h>

// Problem constants
#define NQ 20
#define DIMQ (1 << NQ)          // 2^20
#define NB 16                   // BATCH
#define NT 4                    // N_TERMS
#define RBITS 15                // low bits untouched by gates
#define NCOL (1 << (RBITS + 4)) // 2^15 r-values * 16 batches = 524288 columns

// U table layout in ws/LDS: per (k,b): 36 floats (16 complex interleaved + 4 pad)
//   base = (k*16 + b) * 36 ; entry (i,j): re at base + (i*4+j)*2, im at +1
#define USTRIDE 36
#define UTOT (64 * USTRIDE)     // 2304 floats = 9216 B

// ---------------------------------------------------------------------------
// Kernel A: U[k,b] = exp(-i * H_k * t_{k,b}),  H_k = 0.5*(A + A^H), A = Hr + i Hi
// 256 threads: 64 tasks (k,b) x 4 rows. Scaling (2^-6) + 10-term Taylor + 6 squarings.
// ---------------------------------------------------------------------------
__global__ __launch_bounds__(256) void compute_u_kernel(
    const float* __restrict__ Hre, const float* __restrict__ Him,
    const float* __restrict__ tevo, float* __restrict__ uout) {
  __shared__ float er_s[64][4][4];
  __shared__ float ei_s[64][4][4];

  const int tid  = threadIdx.x;   // 0..255
  const int task = tid >> 2;      // 0..63
  const int row  = tid & 3;       // 0..3
  const int k    = task >> 4;     // 0..3
  const int b    = task & 15;     // 0..15

  float Ar[4][4], Ai[4][4];
#pragma unroll
  for (int i = 0; i < 4; i++) {
#pragma unroll
    for (int j = 0; j < 4; j++) {
      Ar[i][j] = Hre[k * 16 + i * 4 + j];
      Ai[i][j] = Him[k * 16 + i * 4 + j];
    }
  }
  const float t = tevo[k * NB + b];
  const float ts = t * (1.0f / 64.0f);  // scale 2^-6 folded in

  // G = -i * H * ts ; H = 0.5*(A + A^H)
  float Gr[4][4], Gi[4][4];
#pragma unroll
  for (int i = 0; i < 4; i++) {
#pragma unroll
    for (int j = 0; j < 4; j++) {
      const float hr = 0.5f * (Ar[i][j] + Ar[j][i]);
      const float hi = 0.5f * (Ai[i][j] - Ai[j][i]);
      Gr[i][j] = ts * hi;
      Gi[i][j] = -ts * hr;
    }
  }

  // Taylor: E = I + sum_{m=1..10} G^m/m!   (row `row` only; full G in regs)
  float Er[4], Ei[4], Tr[4], Ti[4];
#pragma unroll
  for (int j = 0; j < 4; j++) {
    Er[j] = (j == row) ? 1.0f : 0.0f;
    Ei[j] = 0.0f;
    Tr[j] = Er[j];
    Ti[j] = 0.0f;
  }
#pragma unroll
  for (int m = 1; m <= 10; m++) {
    const float inv = 1.0f / (float)m;
    float nr[4], ni[4];
#pragma unroll
    for (int j = 0; j < 4; j++) {
      float ar = 0.0f, ai = 0.0f;
#pragma unroll
      for (int p = 0; p < 4; p++) {
        ar += Tr[p] * Gr[p][j] - Ti[p] * Gi[p][j];
        ai += Tr[p] * Gi[p][j] + Ti[p] * Gr[p][j];
      }
      nr[j] = ar * inv;
      ni[j] = ai * inv;
    }
#pragma unroll
    for (int j = 0; j < 4; j++) {
      Tr[j] = nr[j]; Ti[j] = ni[j];
      Er[j] += nr[j]; Ei[j] += ni[j];
    }
  }

  // 6 squarings via LDS (uniform trip count -> barriers are safe)
  for (int q = 0; q < 6; q++) {
    __syncthreads();
#pragma unroll
    for (int j = 0; j < 4; j++) {
      er_s[task][row][j] = Er[j];
      ei_s[task][row][j] = Ei[j];
    }
    __syncthreads();
    float nr[4], ni[4];
#pragma unroll
    for (int j = 0; j < 4; j++) {
      float ar = 0.0f, ai = 0.0f;
#pragma unroll
      for (int p = 0; p < 4; p++) {
        ar += Er[p] * er_s[task][p][j] - Ei[p] * ei_s[task][p][j];
        ai += Er[p] * ei_s[task][p][j] + Ei[p] * er_s[task][p][j];
      }
      nr[j] = ar; ni[j] = ai;
    }
#pragma unroll
    for (int j = 0; j < 4; j++) { Er[j] = nr[j]; Ei[j] = ni[j]; }
  }

  // Store U rows: layout [k][b][16 complex interleaved], row stride 36 floats
  const int ubase = (k * 16 + b) * USTRIDE;
#pragma unroll
  for (int j = 0; j < 4; j++) {
    uout[ubase + (row * 4 + j) * 2]     = Er[j];
    uout[ubase + (row * 4 + j) * 2 + 1] = Ei[j];
  }
}

// ---------------------------------------------------------------------------
// Kernel B: out[g,r,b] = sum_k sum_j U[k,b][i(g,k)][j] * s[g'(g,k,j), r, b]
// One thread per column (r,b). 32 complex in regs, 32 complex acc, 4 terms.
// col = r*16+b ; state offset = col + g*2^19 floats.
// ---------------------------------------------------------------------------
__global__ __launch_bounds__(256) void apply_gates_kernel(
    const float* __restrict__ sre, const float* __restrict__ sim,
    const float* __restrict__ u, float* __restrict__ out) {
  __shared__ __align__(16) float ul[UTOT];
  const int tid = threadIdx.x;
  // stage U table (9 KiB) to LDS; UTOT = 9*256 exactly
#pragma unroll
  for (int q = 0; q < 9; q++) ul[tid + q * 256] = u[tid + q * 256];
  __syncthreads();

  const int b = tid & 15;
  const int col = blockIdx.x * 256 + tid;  // r*16 + b

  float s_re[32], s_im[32];
#pragma unroll
  for (int g = 0; g < 32; g++) {
    const int off = col + (g << 19);
    s_re[g] = __builtin_nontemporal_load(sre + off);
    s_im[g] = __builtin_nontemporal_load(sim + off);
  }

  float o_re[32], o_im[32];
#pragma unroll
  for (int g = 0; g < 32; g++) { o_re[g] = 0.0f; o_im[g] = 0.0f; }

#pragma unroll
  for (int k = 0; k < 4; k++) {
    const int sh = 3 - k;  // low bit position of the gate's pair within g
    // Load this (k,b)'s 16 complex U entries: 8 x ds_read_b128, 2-way aliased only
    float uu[32];
    const float* ubase = &ul[(k * 16 + b) * USTRIDE];
#pragma unroll
    for (int q = 0; q < 8; q++) {
      const float4 v = *(const float4*)(ubase + q * 4);
      uu[q * 4 + 0] = v.x; uu[q * 4 + 1] = v.y;
      uu[q * 4 + 2] = v.z; uu[q * 4 + 3] = v.w;
    }
#pragma unroll
    for (int g = 0; g < 32; g++) {
      const int i = (g >> sh) & 3;
      const int gb = g & ~(3 << sh);
#pragma unroll
      for (int j = 0; j < 4; j++) {
        const int src = gb | (j << sh);
        const int p = (i * 4 + j) * 2;
        o_re[g] += uu[p] * s_re[src] - uu[p + 1] * s_im[src];
        o_im[g] += uu[p] * s_im[src] + uu[p + 1] * s_re[src];
      }
    }
  }

#pragma unroll
  for (int g = 0; g < 32; g++) {
    const int off = col + (g << 19);
    __builtin_nontemporal_store(o_re[g], out + off);               // real part
    __builtin_nontemporal_store(o_im[g], out + off + (1 << 24));   // imag part
  }
}

extern "C" void kernel_launch(void* const* d_in, const int* in_sizes, int n_in,
                              void* d_out, int out_size, void* d_ws, size_t ws_size,
                              hipStream_t stream) {
  const float* Hre  = (const float*)d_in[0];
  const float* Him  = (const float*)d_in[1];
  const float* tevo = (const float*)d_in[2];
  const float* sre  = (const float*)d_in[3];
  const float* sim  = (const float*)d_in[4];
  float* out = (float*)d_out;
  float* uws = (float*)d_ws;  // UTOT floats = 9216 B

  compute_u_kernel<<<1, 256, 0, stream>>>(Hre, Him, tevo, uws);
  apply_gates_kernel<<<NCOL / 256, 256, 0, stream>>>(sre, sim, uws, out);
}

// Round 3
// 71.386 us; speedup vs baseline: 1.1422x; 1.1422x over previous
//
#include <hip/hip_runtime.h>

// Problem constants
#define NQ 20
#define DIMQ (1 << NQ)          // 2^20
#define NB 16                   // BATCH
#define NT 4                    // N_TERMS
#define RBITS 15                // low bits untouched by gates
#define NCOL (1 << (RBITS + 4)) // 2^15 r-values * 16 batches = 524288 columns

// U table layout in ws/LDS: per (k,b): 36 floats (16 complex interleaved + 4 pad)
//   base = (k*16 + b) * 36 ; entry (i,j): re at base + (i*4+j)*2, im at +1
#define USTRIDE 36
#define UTOT (64 * USTRIDE)     // 2304 floats = 9216 B

// ---------------------------------------------------------------------------
// Kernel A: U[k,b] = exp(-i * H_k * t_{k,b}),  H_k = 0.5*(A + A^H), A = Hr + i Hi
// 256 threads: 64 tasks (k,b) x 4 rows. Scaling (2^-6) + 10-term Taylor + 6 squarings.
// ---------------------------------------------------------------------------
__global__ __launch_bounds__(256) void compute_u_kernel(
    const float* __restrict__ Hre, const float* __restrict__ Him,
    const float* __restrict__ tevo, float* __restrict__ uout) {
  __shared__ float er_s[64][4][4];
  __shared__ float ei_s[64][4][4];

  const int tid  = threadIdx.x;   // 0..255
  const int task = tid >> 2;      // 0..63
  const int row  = tid & 3;       // 0..3
  const int k    = task >> 4;     // 0..3
  const int b    = task & 15;     // 0..15

  float Ar[4][4], Ai[4][4];
#pragma unroll
  for (int i = 0; i < 4; i++) {
#pragma unroll
    for (int j = 0; j < 4; j++) {
      Ar[i][j] = Hre[k * 16 + i * 4 + j];
      Ai[i][j] = Him[k * 16 + i * 4 + j];
    }
  }
  const float t = tevo[k * NB + b];
  const float ts = t * (1.0f / 64.0f);  // scale 2^-6 folded in

  // G = -i * H * ts ; H = 0.5*(A + A^H)
  float Gr[4][4], Gi[4][4];
#pragma unroll
  for (int i = 0; i < 4; i++) {
#pragma unroll
    for (int j = 0; j < 4; j++) {
      const float hr = 0.5f * (Ar[i][j] + Ar[j][i]);
      const float hi = 0.5f * (Ai[i][j] - Ai[j][i]);
      Gr[i][j] = ts * hi;
      Gi[i][j] = -ts * hr;
    }
  }

  // Taylor: E = I + sum_{m=1..10} G^m/m!   (row `row` only; full G in regs)
  float Er[4], Ei[4], Tr[4], Ti[4];
#pragma unroll
  for (int j = 0; j < 4; j++) {
    Er[j] = (j == row) ? 1.0f : 0.0f;
    Ei[j] = 0.0f;
    Tr[j] = Er[j];
    Ti[j] = 0.0f;
  }
#pragma unroll
  for (int m = 1; m <= 10; m++) {
    const float inv = 1.0f / (float)m;
    float nr[4], ni[4];
#pragma unroll
    for (int j = 0; j < 4; j++) {
      float ar = 0.0f, ai = 0.0f;
#pragma unroll
      for (int p = 0; p < 4; p++) {
        ar += Tr[p] * Gr[p][j] - Ti[p] * Gi[p][j];
        ai += Tr[p] * Gi[p][j] + Ti[p] * Gr[p][j];
      }
      nr[j] = ar * inv;
      ni[j] = ai * inv;
    }
#pragma unroll
    for (int j = 0; j < 4; j++) {
      Tr[j] = nr[j]; Ti[j] = ni[j];
      Er[j] += nr[j]; Ei[j] += ni[j];
    }
  }

  // 6 squarings via LDS (uniform trip count -> barriers are safe)
  for (int q = 0; q < 6; q++) {
    __syncthreads();
#pragma unroll
    for (int j = 0; j < 4; j++) {
      er_s[task][row][j] = Er[j];
      ei_s[task][row][j] = Ei[j];
    }
    __syncthreads();
    float nr[4], ni[4];
#pragma unroll
    for (int j = 0; j < 4; j++) {
      float ar = 0.0f, ai = 0.0f;
#pragma unroll
      for (int p = 0; p < 4; p++) {
        ar += Er[p] * er_s[task][p][j] - Ei[p] * ei_s[task][p][j];
        ai += Er[p] * ei_s[task][p][j] + Ei[p] * er_s[task][p][j];
      }
      nr[j] = ar; ni[j] = ai;
    }
#pragma unroll
    for (int j = 0; j < 4; j++) { Er[j] = nr[j]; Ei[j] = ni[j]; }
  }

  // Store U rows: layout [k][b][16 complex interleaved], row stride 36 floats
  const int ubase = (k * 16 + b) * USTRIDE;
#pragma unroll
  for (int j = 0; j < 4; j++) {
    uout[ubase + (row * 4 + j) * 2]     = Er[j];
    uout[ubase + (row * 4 + j) * 2 + 1] = Ei[j];
  }
}

// ---------------------------------------------------------------------------
// Kernel B: out[g,r,b] = sum_k sum_j U[k,b][i(g,k)][j] * s[g'(g,k,j), r, b]
// One thread per column (r,b). 32 complex state + 32 complex acc in regs.
// Inner structure: for k, for U-row i (8 floats live), for the 8 g's with
// that i. Live set ~150 floats; __launch_bounds__(256,2) -> 256-VGPR budget,
// no spill, 2 waves/SIMD.
// ---------------------------------------------------------------------------
__global__ __launch_bounds__(256, 2) void apply_gates_kernel(
    const float* __restrict__ sre, const float* __restrict__ sim,
    const float* __restrict__ u, float* __restrict__ out) {
  __shared__ __align__(16) float ul[UTOT];
  const int tid = threadIdx.x;
  // stage U table (9 KiB) to LDS; UTOT = 9*256 exactly
#pragma unroll
  for (int q = 0; q < 9; q++) ul[tid + q * 256] = u[tid + q * 256];
  __syncthreads();

  const int b = tid & 15;
  const int col = blockIdx.x * 256 + tid;  // r*16 + b

  float s_re[32], s_im[32];
#pragma unroll
  for (int g = 0; g < 32; g++) {
    const int off = col + (g << 19);
    s_re[g] = sre[off];
    s_im[g] = sim[off];
  }

  float o_re[32], o_im[32];
#pragma unroll
  for (int g = 0; g < 32; g++) { o_re[g] = 0.0f; o_im[g] = 0.0f; }

#pragma unroll
  for (int k = 0; k < 4; k++) {
    const int sh = 3 - k;  // low bit position of the gate's pair within g
    const float* ubase = &ul[(k * 16 + b) * USTRIDE];
#pragma unroll
    for (int i = 0; i < 4; i++) {
      // U row i for this (k,b): 4 complex entries = 8 floats = 2 x ds_read_b128
      const float4 v0 = *(const float4*)(ubase + i * 8);
      const float4 v1 = *(const float4*)(ubase + i * 8 + 4);
      const float ur0 = v0.x, ui0 = v0.y, ur1 = v0.z, ui1 = v0.w;
      const float ur2 = v1.x, ui2 = v1.y, ur3 = v1.z, ui3 = v1.w;
      // The 8 outputs g with (g>>sh)&3 == i: insert 2 bits of i at position sh
#pragma unroll
      for (int gg = 0; gg < 8; gg++) {
        const int low = gg & ((1 << sh) - 1);
        const int high = (gg >> sh) << (sh + 2);
        const int gb = high | low;           // g with the pair bits cleared
        const int g = gb | (i << sh);
        const int s0 = gb;                   // j = 0
        const int s1 = gb | (1 << sh);       // j = 1
        const int s2 = gb | (2 << sh);       // j = 2
        const int s3 = gb | (3 << sh);       // j = 3
        o_re[g] += ur0 * s_re[s0] - ui0 * s_im[s0]
                 + ur1 * s_re[s1] - ui1 * s_im[s1]
                 + ur2 * s_re[s2] - ui2 * s_im[s2]
                 + ur3 * s_re[s3] - ui3 * s_im[s3];
        o_im[g] += ur0 * s_im[s0] + ui0 * s_re[s0]
                 + ur1 * s_im[s1] + ui1 * s_re[s1]
                 + ur2 * s_im[s2] + ui2 * s_re[s2]
                 + ur3 * s_im[s3] + ui3 * s_re[s3];
      }
    }
  }

#pragma unroll
  for (int g = 0; g < 32; g++) {
    const int off = col + (g << 19);
    __builtin_nontemporal_store(o_re[g], out + off);               // real part
    __builtin_nontemporal_store(o_im[g], out + off + (1 << 24));   // imag part
  }
}

extern "C" void kernel_launch(void* const* d_in, const int* in_sizes, int n_in,
                              void* d_out, int out_size, void* d_ws, size_t ws_size,
                              hipStream_t stream) {
  const float* Hre  = (const float*)d_in[0];
  const float* Him  = (const float*)d_in[1];
  const float* tevo = (const float*)d_in[2];
  const float* sre  = (const float*)d_in[3];
  const float* sim  = (const float*)d_in[4];
  float* out = (float*)d_out;
  float* uws = (float*)d_ws;  // UTOT floats = 9216 B

  compute_u_kernel<<<1, 256, 0, stream>>>(Hre, Him, tevo, uws);
  apply_gates_kernel<<<NCOL / 256, 256, 0, stream>>>(sre, sim, uws, out);
}